// Round 1
// baseline (537.295 us; speedup 1.0000x reference)
//
#include <hip/hip_runtime.h>
#include <math.h>

// Problem constants (from reference): x shape (5, 512, 128, 256) fp32.
#define KMAX   5        // max_cav
#define NC     512      // FEATURE_DIM
#define HW     32768    // 128*256 spatial positions
#define NCHUNK 8        // c-chunks for partial-dot kernel
#define CPC    (NC / NCHUNK)   // 64 channels per chunk
#define INV_SQRT_DIM 0.044194173824159216f  // 1/sqrt(512)

__device__ __forceinline__ int clamp_K(const int* __restrict__ rlp) {
    int K = *rlp;                 // wave-uniform scalar load (L2-cached)
    return K < 0 ? 0 : (K > KMAX ? KMAX : K);
}

// ---------------------------------------------------------------------------
// K1: partial dot products dot_k(b) over a c-chunk.
// Thread handles 4 consecutive b's via float4 (coalesced 1KiB/wave loads).
// grid = (HW/4/256, NCHUNK), block = 256.
// partial layout: partial[(chunk*KMAX + k)*HW + b]
// ---------------------------------------------------------------------------
__global__ void k1_partial_dots(const float* __restrict__ x,
                                const int* __restrict__ rlp,
                                float* __restrict__ partial) {
    const int b4    = blockIdx.x * blockDim.x + threadIdx.x;  // 0..HW/4-1
    const int chunk = blockIdx.y;
    const int K     = clamp_K(rlp);
    const float4* xv = (const float4*)x;

    float4 d[KMAX];
#pragma unroll
    for (int k = 0; k < KMAX; ++k) d[k] = make_float4(0.f, 0.f, 0.f, 0.f);

    const int c0 = chunk * CPC;
#pragma unroll 4
    for (int c = c0; c < c0 + CPC; ++c) {
        const float4 x0 = xv[(size_t)c * (HW / 4) + b4];
        d[0].x += x0.x * x0.x; d[0].y += x0.y * x0.y;
        d[0].z += x0.z * x0.z; d[0].w += x0.w * x0.w;
#pragma unroll
        for (int k = 1; k < KMAX; ++k) {
            if (k < K) {
                const float4 xk = xv[((size_t)k * NC + c) * (HW / 4) + b4];
                d[k].x += x0.x * xk.x; d[k].y += x0.y * xk.y;
                d[k].z += x0.z * xk.z; d[k].w += x0.w * xk.w;
            }
        }
    }

    float4* pv = (float4*)partial;
#pragma unroll
    for (int k = 0; k < KMAX; ++k)
        if (k < K) pv[((size_t)chunk * KMAX + k) * (HW / 4) + b4] = d[k];
}

// ---------------------------------------------------------------------------
// K2: reduce chunk partials, masked softmax over k, write attn[k*HW + b].
// grid = HW/256, block = 256.
// ---------------------------------------------------------------------------
__global__ void k2_softmax(const float* __restrict__ partial,
                           const int* __restrict__ rlp,
                           float* __restrict__ attn) {
    const int b = blockIdx.x * blockDim.x + threadIdx.x;  // 0..HW-1
    const int K = clamp_K(rlp);

    float d[KMAX];
#pragma unroll
    for (int k = 0; k < KMAX; ++k) d[k] = 0.f;
    for (int ch = 0; ch < NCHUNK; ++ch) {
#pragma unroll
        for (int k = 0; k < KMAX; ++k)
            if (k < K) d[k] += partial[((size_t)ch * KMAX + k) * HW + b];
    }

    float m = -INFINITY;
#pragma unroll
    for (int k = 0; k < KMAX; ++k)
        if (k < K) { d[k] *= INV_SQRT_DIM; if (d[k] > m) m = d[k]; }
    float s = 0.f;
#pragma unroll
    for (int k = 0; k < KMAX; ++k)
        if (k < K) { d[k] = expf(d[k] - m); s += d[k]; }
    const float inv = (K > 0) ? 1.f / s : 0.f;  // K==0 -> nan_to_num -> 0
#pragma unroll
    for (int k = 0; k < KMAX; ++k)
        attn[(size_t)k * HW + b] = (k < K) ? d[k] * inv : 0.f;
}

// ---------------------------------------------------------------------------
// K1-fallback (small ws): full dots + softmax in one kernel, writes attn only.
// grid = HW/4/256, block = 256.
// ---------------------------------------------------------------------------
__global__ void k1_full_softmax(const float* __restrict__ x,
                                const int* __restrict__ rlp,
                                float* __restrict__ attn) {
    const int b4 = blockIdx.x * blockDim.x + threadIdx.x;
    const int K  = clamp_K(rlp);
    const float4* xv = (const float4*)x;

    float4 d[KMAX];
#pragma unroll
    for (int k = 0; k < KMAX; ++k) d[k] = make_float4(0.f, 0.f, 0.f, 0.f);

#pragma unroll 4
    for (int c = 0; c < NC; ++c) {
        const float4 x0 = xv[(size_t)c * (HW / 4) + b4];
        d[0].x += x0.x * x0.x; d[0].y += x0.y * x0.y;
        d[0].z += x0.z * x0.z; d[0].w += x0.w * x0.w;
#pragma unroll
        for (int k = 1; k < KMAX; ++k) {
            if (k < K) {
                const float4 xk = xv[((size_t)k * NC + c) * (HW / 4) + b4];
                d[k].x += x0.x * xk.x; d[k].y += x0.y * xk.y;
                d[k].z += x0.z * xk.z; d[k].w += x0.w * xk.w;
            }
        }
    }

    float4 m = make_float4(-INFINITY, -INFINITY, -INFINITY, -INFINITY);
#pragma unroll
    for (int k = 0; k < KMAX; ++k)
        if (k < K) {
            d[k].x *= INV_SQRT_DIM; d[k].y *= INV_SQRT_DIM;
            d[k].z *= INV_SQRT_DIM; d[k].w *= INV_SQRT_DIM;
            m.x = fmaxf(m.x, d[k].x); m.y = fmaxf(m.y, d[k].y);
            m.z = fmaxf(m.z, d[k].z); m.w = fmaxf(m.w, d[k].w);
        }
    float4 s = make_float4(0.f, 0.f, 0.f, 0.f);
#pragma unroll
    for (int k = 0; k < KMAX; ++k)
        if (k < K) {
            d[k].x = expf(d[k].x - m.x); d[k].y = expf(d[k].y - m.y);
            d[k].z = expf(d[k].z - m.z); d[k].w = expf(d[k].w - m.w);
            s.x += d[k].x; s.y += d[k].y; s.z += d[k].z; s.w += d[k].w;
        }
    float4 inv = make_float4(0.f, 0.f, 0.f, 0.f);
    if (K > 0) { inv.x = 1.f / s.x; inv.y = 1.f / s.y; inv.z = 1.f / s.z; inv.w = 1.f / s.w; }

    float4* av = (float4*)attn;
#pragma unroll
    for (int k = 0; k < KMAX; ++k) {
        float4 a = make_float4(0.f, 0.f, 0.f, 0.f);
        if (k < K) {
            a.x = d[k].x * inv.x; a.y = d[k].y * inv.y;
            a.z = d[k].z * inv.z; a.w = d[k].w * inv.w;
        }
        av[(size_t)k * (HW / 4) + b4] = a;
    }
}

// ---------------------------------------------------------------------------
// K3: out[c,b] = sum_k attn[k,b] * x[k,c,b], float4 over b.
// grid = NC*HW/4/256 = 16384, block = 256.
// ---------------------------------------------------------------------------
__global__ void k3_out(const float* __restrict__ x,
                       const int* __restrict__ rlp,
                       const float* __restrict__ attn,
                       float* __restrict__ out) {
    const int idx = blockIdx.x * blockDim.x + threadIdx.x;  // 0..NC*HW/4-1
    const int b4  = idx & (HW / 4 - 1);
    const int c   = idx >> 13;                              // HW/4 = 8192 = 2^13
    const int K   = clamp_K(rlp);

    const float4* xv = (const float4*)x;
    const float4* av = (const float4*)attn;

    float4 acc = make_float4(0.f, 0.f, 0.f, 0.f);
#pragma unroll
    for (int k = 0; k < KMAX; ++k) {
        if (k < K) {
            const float4 a  = av[(size_t)k * (HW / 4) + b4];
            const float4 xk = xv[((size_t)k * NC + c) * (HW / 4) + b4];
            acc.x += a.x * xk.x; acc.y += a.y * xk.y;
            acc.z += a.z * xk.z; acc.w += a.w * xk.w;
        }
    }
    ((float4*)out)[(size_t)c * (HW / 4) + b4] = acc;
}

extern "C" void kernel_launch(void* const* d_in, const int* in_sizes, int n_in,
                              void* d_out, int out_size, void* d_ws, size_t ws_size,
                              hipStream_t stream) {
    const float* x  = (const float*)d_in[0];
    const int*   rl = (const int*)d_in[1];
    float*       out = (float*)d_out;
    float*       ws  = (float*)d_ws;

    const size_t partial_elems = (size_t)NCHUNK * KMAX * HW;  // 1.31M floats
    const size_t attn_elems    = (size_t)KMAX * HW;           // 164K floats

    if (ws_size >= (partial_elems + attn_elems) * sizeof(float)) {
        float* partial = ws;
        float* attn    = ws + partial_elems;
        k1_partial_dots<<<dim3((HW / 4) / 256, NCHUNK), 256, 0, stream>>>(x, rl, partial);
        k2_softmax<<<HW / 256, 256, 0, stream>>>(partial, rl, attn);
        k3_out<<<(NC * (HW / 4)) / 256, 256, 0, stream>>>(x, rl, attn, out);
    } else {
        // Fallback: only needs 640 KB of ws.
        float* attn = ws;
        k1_full_softmax<<<(HW / 4) / 256, 256, 0, stream>>>(x, rl, attn);
        k3_out<<<(NC * (HW / 4)) / 256, 256, 0, stream>>>(x, rl, attn, out);
    }
}

// Round 2
// 493.850 us; speedup vs baseline: 1.0880x; 1.0880x over previous
//
#include <hip/hip_runtime.h>
#include <math.h>

// Problem constants (from reference): x shape (5, 512, 128, 256) fp32.
#define KMAX   5        // max_cav
#define NC     512      // FEATURE_DIM
#define HW     32768    // 128*256 spatial positions
#define NCHUNK 32       // c-chunks for partial-dot kernel (32 -> 1024 blocks)
#define CPC    (NC / NCHUNK)   // 16 channels per chunk
#define INV_SQRT_DIM 0.044194173824159216f  // 1/sqrt(512)

__device__ __forceinline__ int clamp_K(const int* __restrict__ rlp) {
    int K = *rlp;                 // wave-uniform scalar load (L2-cached)
    return K < 0 ? 0 : (K > KMAX ? KMAX : K);
}

// ---------------------------------------------------------------------------
// K1: partial dot products dot_k(b) over a c-chunk, templated on K so the
// c-loop is branch-free and fully software-pipelined.
// grid = (HW/4/256, NCHUNK), block = 256.  partial[(chunk*KMAX+k)*HW + b]
// ---------------------------------------------------------------------------
template <int K>
__device__ __forceinline__ void k1_dots_body(const float4* __restrict__ xv,
                                             float4* __restrict__ pv,
                                             int b4, int chunk) {
    float4 d[K];
#pragma unroll
    for (int k = 0; k < K; ++k) d[k] = make_float4(0.f, 0.f, 0.f, 0.f);

    const int c0 = chunk * CPC;
#pragma unroll 4
    for (int i = 0; i < CPC; ++i) {
        const int c = c0 + i;
        const float4 x0 = xv[(size_t)c * (HW / 4) + b4];
        d[0].x += x0.x * x0.x; d[0].y += x0.y * x0.y;
        d[0].z += x0.z * x0.z; d[0].w += x0.w * x0.w;
#pragma unroll
        for (int k = 1; k < K; ++k) {
            const float4 xk = xv[((size_t)k * NC + c) * (HW / 4) + b4];
            d[k].x += x0.x * xk.x; d[k].y += x0.y * xk.y;
            d[k].z += x0.z * xk.z; d[k].w += x0.w * xk.w;
        }
    }
#pragma unroll
    for (int k = 0; k < K; ++k)
        pv[((size_t)chunk * KMAX + k) * (HW / 4) + b4] = d[k];
}

__global__ void k1_partial_dots(const float* __restrict__ x,
                                const int* __restrict__ rlp,
                                float* __restrict__ partial) {
    const int b4    = blockIdx.x * blockDim.x + threadIdx.x;  // 0..HW/4-1
    const int chunk = blockIdx.y;
    const int K     = clamp_K(rlp);
    const float4* xv = (const float4*)x;
    float4*       pv = (float4*)partial;
    switch (K) {                       // wave-uniform branch
        case 1: k1_dots_body<1>(xv, pv, b4, chunk); break;
        case 2: k1_dots_body<2>(xv, pv, b4, chunk); break;
        case 3: k1_dots_body<3>(xv, pv, b4, chunk); break;
        case 4: k1_dots_body<4>(xv, pv, b4, chunk); break;
        case 5: k1_dots_body<5>(xv, pv, b4, chunk); break;
        default: break;                // K==0: nothing to write
    }
}

// ---------------------------------------------------------------------------
// K2: reduce chunk partials, masked softmax over k, write attn[k*HW + b].
// grid = HW/256, block = 256.
// ---------------------------------------------------------------------------
template <int K>
__device__ __forceinline__ void k2_body(const float* __restrict__ partial,
                                        float* __restrict__ attn, int b) {
    float d[K];
#pragma unroll
    for (int k = 0; k < K; ++k) d[k] = 0.f;
#pragma unroll 4
    for (int ch = 0; ch < NCHUNK; ++ch) {
#pragma unroll
        for (int k = 0; k < K; ++k)
            d[k] += partial[((size_t)ch * KMAX + k) * HW + b];
    }
    float m = -INFINITY;
#pragma unroll
    for (int k = 0; k < K; ++k) { d[k] *= INV_SQRT_DIM; m = fmaxf(m, d[k]); }
    float s = 0.f;
#pragma unroll
    for (int k = 0; k < K; ++k) { d[k] = expf(d[k] - m); s += d[k]; }
    const float inv = 1.f / s;
#pragma unroll
    for (int k = 0; k < KMAX; ++k)
        attn[(size_t)k * HW + b] = (k < K) ? d[k] * inv : 0.f;
}

__global__ void k2_softmax(const float* __restrict__ partial,
                           const int* __restrict__ rlp,
                           float* __restrict__ attn) {
    const int b = blockIdx.x * blockDim.x + threadIdx.x;  // 0..HW-1
    const int K = clamp_K(rlp);
    switch (K) {
        case 1: k2_body<1>(partial, attn, b); break;
        case 2: k2_body<2>(partial, attn, b); break;
        case 3: k2_body<3>(partial, attn, b); break;
        case 4: k2_body<4>(partial, attn, b); break;
        case 5: k2_body<5>(partial, attn, b); break;
        default:                                // K==0 -> nan_to_num -> 0
#pragma unroll
            for (int k = 0; k < KMAX; ++k) attn[(size_t)k * HW + b] = 0.f;
            break;
    }
}

// ---------------------------------------------------------------------------
// K3: out[c,b] = sum_k attn[k,b] * x[k,c,b], float4 over b.
// grid = NC*HW/4/256 = 16384, block = 256.
// ---------------------------------------------------------------------------
template <int K>
__device__ __forceinline__ void k3_body(const float4* __restrict__ xv,
                                        const float4* __restrict__ av,
                                        float4* __restrict__ outv,
                                        int b4, int c) {
    float4 acc = make_float4(0.f, 0.f, 0.f, 0.f);
#pragma unroll
    for (int k = 0; k < K; ++k) {
        const float4 a  = av[(size_t)k * (HW / 4) + b4];
        const float4 xk = xv[((size_t)k * NC + c) * (HW / 4) + b4];
        acc.x += a.x * xk.x; acc.y += a.y * xk.y;
        acc.z += a.z * xk.z; acc.w += a.w * xk.w;
    }
    outv[(size_t)c * (HW / 4) + b4] = acc;
}

__global__ void k3_out(const float* __restrict__ x,
                       const int* __restrict__ rlp,
                       const float* __restrict__ attn,
                       float* __restrict__ out) {
    const int idx = blockIdx.x * blockDim.x + threadIdx.x;  // 0..NC*HW/4-1
    const int b4  = idx & (HW / 4 - 1);
    const int c   = idx >> 13;                              // HW/4 = 8192 = 2^13
    const int K   = clamp_K(rlp);
    const float4* xv   = (const float4*)x;
    const float4* av   = (const float4*)attn;
    float4*       outv = (float4*)out;
    switch (K) {
        case 1: k3_body<1>(xv, av, outv, b4, c); break;
        case 2: k3_body<2>(xv, av, outv, b4, c); break;
        case 3: k3_body<3>(xv, av, outv, b4, c); break;
        case 4: k3_body<4>(xv, av, outv, b4, c); break;
        case 5: k3_body<5>(xv, av, outv, b4, c); break;
        default:
            outv[(size_t)c * (HW / 4) + b4] = make_float4(0.f, 0.f, 0.f, 0.f);
            break;
    }
}

// ---------------------------------------------------------------------------
// Fallback (tiny ws): full dots + softmax in one kernel, writes attn only.
// grid = HW/4/256, block = 256. Slow (low occupancy) but only needs 640 KB.
// ---------------------------------------------------------------------------
__global__ void k1_full_softmax(const float* __restrict__ x,
                                const int* __restrict__ rlp,
                                float* __restrict__ attn) {
    const int b4 = blockIdx.x * blockDim.x + threadIdx.x;
    const int K  = clamp_K(rlp);
    const float4* xv = (const float4*)x;

    float4 d[KMAX];
#pragma unroll
    for (int k = 0; k < KMAX; ++k) d[k] = make_float4(0.f, 0.f, 0.f, 0.f);

#pragma unroll 4
    for (int c = 0; c < NC; ++c) {
        const float4 x0 = xv[(size_t)c * (HW / 4) + b4];
        d[0].x += x0.x * x0.x; d[0].y += x0.y * x0.y;
        d[0].z += x0.z * x0.z; d[0].w += x0.w * x0.w;
#pragma unroll
        for (int k = 1; k < KMAX; ++k) {
            if (k < K) {
                const float4 xk = xv[((size_t)k * NC + c) * (HW / 4) + b4];
                d[k].x += x0.x * xk.x; d[k].y += x0.y * xk.y;
                d[k].z += x0.z * xk.z; d[k].w += x0.w * xk.w;
            }
        }
    }

    float4 m = make_float4(-INFINITY, -INFINITY, -INFINITY, -INFINITY);
#pragma unroll
    for (int k = 0; k < KMAX; ++k)
        if (k < K) {
            d[k].x *= INV_SQRT_DIM; d[k].y *= INV_SQRT_DIM;
            d[k].z *= INV_SQRT_DIM; d[k].w *= INV_SQRT_DIM;
            m.x = fmaxf(m.x, d[k].x); m.y = fmaxf(m.y, d[k].y);
            m.z = fmaxf(m.z, d[k].z); m.w = fmaxf(m.w, d[k].w);
        }
    float4 s = make_float4(0.f, 0.f, 0.f, 0.f);
#pragma unroll
    for (int k = 0; k < KMAX; ++k)
        if (k < K) {
            d[k].x = expf(d[k].x - m.x); d[k].y = expf(d[k].y - m.y);
            d[k].z = expf(d[k].z - m.z); d[k].w = expf(d[k].w - m.w);
            s.x += d[k].x; s.y += d[k].y; s.z += d[k].z; s.w += d[k].w;
        }
    float4 inv = make_float4(0.f, 0.f, 0.f, 0.f);
    if (K > 0) { inv.x = 1.f / s.x; inv.y = 1.f / s.y; inv.z = 1.f / s.z; inv.w = 1.f / s.w; }

    float4* av = (float4*)attn;
#pragma unroll
    for (int k = 0; k < KMAX; ++k) {
        float4 a = make_float4(0.f, 0.f, 0.f, 0.f);
        if (k < K) {
            a.x = d[k].x * inv.x; a.y = d[k].y * inv.y;
            a.z = d[k].z * inv.z; a.w = d[k].w * inv.w;
        }
        av[(size_t)k * (HW / 4) + b4] = a;
    }
}

extern "C" void kernel_launch(void* const* d_in, const int* in_sizes, int n_in,
                              void* d_out, int out_size, void* d_ws, size_t ws_size,
                              hipStream_t stream) {
    const float* x   = (const float*)d_in[0];
    const int*   rl  = (const int*)d_in[1];
    float*       out = (float*)d_out;
    float*       ws  = (float*)d_ws;

    const size_t partial_elems = (size_t)NCHUNK * KMAX * HW;  // 5.24M floats (21 MB)
    const size_t attn_elems    = (size_t)KMAX * HW;           // 164K floats (640 KB)

    if (ws_size >= (partial_elems + attn_elems) * sizeof(float)) {
        float* partial = ws;
        float* attn    = ws + partial_elems;
        k1_partial_dots<<<dim3((HW / 4) / 256, NCHUNK), 256, 0, stream>>>(x, rl, partial);
        k2_softmax<<<HW / 256, 256, 0, stream>>>(partial, rl, attn);
        k3_out<<<(NC * (HW / 4)) / 256, 256, 0, stream>>>(x, rl, attn, out);
    } else {
        // Fallback: only needs 640 KB of ws.
        float* attn = ws;
        k1_full_softmax<<<(HW / 4) / 256, 256, 0, stream>>>(x, rl, attn);
        k3_out<<<(NC * (HW / 4)) / 256, 256, 0, stream>>>(x, rl, attn, out);
    }
}